// Round 9
// baseline (224.312 us; speedup 1.0000x reference)
//
#include <hip/hip_runtime.h>
#include <hip/hip_bf16.h>
#include <cstdint>
#include <cstddef>

// Problem constants (shapes fixed by the reference)
#define NN      10000      // nodes (M == N == 10000)
#define DD      256        // feature dim
#define KSTEPS  313        // ceil(10016/32) K-steps of 32
#define MB64    157        // ceil(10000/64) m-blocks for big GEMM (BM=64)
#define KSPLIT  6          // 157*6 = 942 blocks ~= 3.7/CU at 4 blocks/CU occupancy

typedef __bf16 bf16x8 __attribute__((ext_vector_type(8)));
typedef float  f32x4  __attribute__((ext_vector_type(4)));

// ---- workspace layout (bytes) ----
#define XG_OFF   0ull
#define XG_SIZE  (32ull * 10000 * 16)        // [q=kb*4+g][row] 16B chunks (bf16 X, MFMA-A layout)
#define WG_OFF   (XG_OFF + XG_SIZE)
#define WG_SIZE  (32ull * 256 * 16)          // [q][n] chunks (bf16 W, MFMA-B layout)
#define INP_OFF  (WG_OFF + WG_SIZE)
#define INP_SIZE (10000ull * 256 * 4)        // inp = X@W, f32
#define E_OFF    (INP_OFF + INP_SIZE)
#define E_SIZE   (10016ull * 4)
#define HS_OFF   (E_OFF + E_SIZE)
#define HS_SIZE  (10016ull * 4)
#define G_OFF    (HS_OFF + HS_SIZE)
#define G_SIZE   (10016ull * 4)
#define YG_OFF   (G_OFF + G_SIZE + 256ull)   // keep 256B alignment
#define YG_SIZE  (318ull * 1088 * 16)        // [kb32][chunk]; kb 313..317 zero pads
#define PN_OFF   (YG_OFF + YG_SIZE)
#define PN_SIZE  ((size_t)KSPLIT * 10000 * 272 * 4)  // per-kc partials: 256 numer cols + den at col 256

// async global(16B) -> LDS copy; dest = wave-uniform base + lane*16
__device__ __forceinline__ void gl_lds16(const void* g, void* lds) {
    __builtin_amdgcn_global_load_lds(
        (const __attribute__((address_space(1))) unsigned int*)g,
        (__attribute__((address_space(3))) unsigned int*)lds,
        16, 0, 0);
}

// ---------------- K0a: build XG (bf16 X in MFMA-A chunk layout) ----------------
__global__ __launch_bounds__(256) void k_build_xg(const float* __restrict__ X,
                                                  bf16x8* __restrict__ XG) {
    int idx = blockIdx.x * 256 + threadIdx.x;   // 0..319999
    int row = idx >> 5;
    int q   = idx & 31;
    const float* src = X + row * 256 + q * 8;
    bf16x8 v;
#pragma unroll
    for (int j = 0; j < 8; ++j) v[j] = (__bf16)src[j];
    XG[q * 10000 + row] = v;
}

// ---------------- K0b: build WG (bf16 W in MFMA-B chunk layout) ----------------
__global__ __launch_bounds__(256) void k_build_wg(const float* __restrict__ W,
                                                  bf16x8* __restrict__ WG) {
    int e = blockIdx.x * 256 + threadIdx.x;     // 0..8191
    int q = e >> 8;
    int n = e & 255;
    bf16x8 v;
#pragma unroll
    for (int j = 0; j < 8; ++j) v[j] = (__bf16)W[(q * 8 + j) * 256 + n];
    WG[e] = v;
}

// ---------------- K1: inp = X@W (MFMA), fused tanh/e/hsum (LDS cross-wave reduce) ----------------
__global__ __launch_bounds__(256) void k_gemm1(const bf16x8* __restrict__ XG,
                                               const bf16x8* __restrict__ WG,
                                               const float* __restrict__ bvec,
                                               const float* __restrict__ avec,
                                               float* __restrict__ inp,
                                               float* __restrict__ evec,
                                               float* __restrict__ hsumv) {
    __shared__ bf16x8 Ash[320];    // (g*80 + r)
    __shared__ bf16x8 Bsh[1024];   // (g*256 + n)
    __shared__ float ePart[4][80];
    __shared__ float hPart[4][80];
    int tid = threadIdx.x, wid = tid >> 6, lane = tid & 63;
    int l15 = lane & 15, l4 = lane >> 4;
    int mb = blockIdx.x;

    f32x4 acc[4][5];
#pragma unroll
    for (int c = 0; c < 4; ++c)
#pragma unroll
        for (int rt = 0; rt < 5; ++rt) acc[c][rt] = f32x4{0.f, 0.f, 0.f, 0.f};

    for (int kb = 0; kb < 8; ++kb) {
        for (int rr = wid; rr < 5; rr += 4) {
            int c = rr * 64 + lane;
            int g = c / 80, r = c - g * 80;
            gl_lds16(XG + ((kb * 4 + g) * 10000 + mb * 80 + r), (char*)Ash + rr * 1024);
        }
        for (int rr = wid; rr < 16; rr += 4)
            gl_lds16(WG + kb * 1024 + rr * 64 + lane, (char*)Bsh + rr * 1024);
        __syncthreads();

        bf16x8 af[5];
#pragma unroll
        for (int rt = 0; rt < 5; ++rt) af[rt] = Ash[l4 * 80 + rt * 16 + l15];
#pragma unroll
        for (int c = 0; c < 4; ++c) {
            bf16x8 bf = Bsh[l4 * 256 + (wid * 4 + c) * 16 + l15];
#pragma unroll
            for (int rt = 0; rt < 5; ++rt)
                acc[c][rt] = __builtin_amdgcn_mfma_f32_16x16x32_bf16(af[rt], bf, acc[c][rt], 0, 0, 0);
        }
        __syncthreads();
    }

    float pe[5][4], ph[5][4];
#pragma unroll
    for (int rt = 0; rt < 5; ++rt)
#pragma unroll
        for (int rg = 0; rg < 4; ++rg) { pe[rt][rg] = 0.f; ph[rt][rg] = 0.f; }

#pragma unroll
    for (int c = 0; c < 4; ++c) {
        int col = (wid * 4 + c) * 16 + l15;
        float av = avec[col];
        float bv = bvec[col];
#pragma unroll
        for (int rt = 0; rt < 5; ++rt) {
#pragma unroll
            for (int rg = 0; rg < 4; ++rg) {
                int row = mb * 80 + rt * 16 + l4 * 4 + rg;
                float v = acc[c][rt][rg];            // inp excludes bias (per reference)
                inp[row * 256 + col] = v;
                float h = tanhf(v + bv);
                pe[rt][rg] += h * av;
                ph[rt][rg] += h;
            }
        }
    }
#pragma unroll
    for (int rt = 0; rt < 5; ++rt) {
#pragma unroll
        for (int rg = 0; rg < 4; ++rg) {
            float se = pe[rt][rg], sh = ph[rt][rg];
#pragma unroll
            for (int m = 1; m < 16; m <<= 1) {
                se += __shfl_xor(se, m);
                sh += __shfl_xor(sh, m);
            }
            if (l15 == 0) {
                int lr = rt * 16 + l4 * 4 + rg;   // 0..79
                ePart[wid][lr] = se;
                hPart[wid][lr] = sh;
            }
        }
    }
    __syncthreads();
    if (tid < 80) {
        float e = ePart[0][tid] + ePart[1][tid] + ePart[2][tid] + ePart[3][tid];
        float h = hPart[0][tid] + hPart[1][tid] + hPart[2][tid] + hPart[3][tid];
        evec[mb * 80 + tid] = e;
        hsumv[mb * 80 + tid] = h;
    }
}

// ---------------- K2: global max of e over valid nodes, then g = exp(e-gmax) ----------------
__global__ __launch_bounds__(1024) void k_softmax_g(const float* __restrict__ evec,
                                                    const float* __restrict__ hsumv,
                                                    float* __restrict__ gv) {
    __shared__ float red[1024];
    int tid = threadIdx.x;
    float m = -3.0e38f;
    for (int i = tid; i < NN; i += 1024)
        if (hsumv[i] != 0.0f) m = fmaxf(m, evec[i]);
    red[tid] = m;
    __syncthreads();
    for (int s = 512; s > 0; s >>= 1) {
        if (tid < s) red[tid] = fmaxf(red[tid], red[tid + s]);
        __syncthreads();
    }
    float gmax = red[0];
    if (gmax < -1.0e37f) gmax = 0.0f;
    for (int i = tid; i < 10016; i += 1024) {
        float g = 0.0f;
        if (i < NN && hsumv[i] != 0.0f) g = expf(evec[i] - gmax);
        gv[i] = g;
    }
}

// ---------------- K3: build YG = pre-chunked bf16 B tiles for the big GEMM ----------------
// grid 318: kb >= 313 hits the k<NN guard everywhere -> zero pads
__global__ __launch_bounds__(256) void k_build_yg(const float* __restrict__ inp,
                                                  const float* __restrict__ gv,
                                                  bf16x8* __restrict__ YG) {
    int kb = blockIdx.x;   // 0..317
    for (int c = threadIdx.x; c < 1088; c += 256) {
        int gq = c / 272, n = c - gq * 272;
        int k0 = kb * 32 + gq * 8;
        bf16x8 v;
#pragma unroll
        for (int j = 0; j < 8; ++j) {
            int k = k0 + j;
            float val = 0.0f;
            if (k < NN) {
                float gk = gv[k];
                if (n < 256) val = gk * inp[k * 256 + n];
                else if (n == 256) val = gk;
            }
            v[j] = (__bf16)val;
        }
        YG[kb * 1088 + c] = v;
    }
}

// ---- int32 {0,1} pair-of-int4 -> bf16x8 {0,1} fragment ----
__device__ __forceinline__ bf16x8 cvt_adj(int4 a, int4 b) {
    union { bf16x8 v; unsigned int u[4]; } r;
    r.u[0] = (a.x > 0 ? 0x3F80u : 0u) | (a.y > 0 ? 0x3F800000u : 0u);
    r.u[1] = (a.z > 0 ? 0x3F80u : 0u) | (a.w > 0 ? 0x3F800000u : 0u);
    r.u[2] = (b.x > 0 ? 0x3F80u : 0u) | (b.y > 0 ? 0x3F800000u : 0u);
    r.u[3] = (b.z > 0 ? 0x3F80u : 0u) | (b.w > 0 ? 0x3F800000u : 0u);
    return r.v;
}

// ---------------- K4: num_kc = adj @ Y  (OCCUPANCY-FIRST: 4 blocks/CU, 16 waves) ----------------
// BM=64, 4 waves x 16 rows (1 row-tile each), all 17 col-tiles per wave: acc[17]=68
// regs -> ~112 total -> 4 waves/SIMD. BK=32: LDS dbuf 34.8 KB -> 4 blocks/CU by LDS.
// The R3-R8 plateau at 8 waves/CU was TLP-starved (R6 proved the loop isn't BW-bound:
// removing 97% of A traffic didn't help). 16 waves/CU of independent blocks hide the
// per-step stalls (m114/m97 pattern). Same proven 2-barrier cadence: stage B(s+1) via
// gl_lds, A 1-step prefetch in regs, counted vmcnt(2) (drains own gl_lds, keeps A).
__global__ __launch_bounds__(256, 4) void k_attn_gemm(const int* __restrict__ adj,
                                                      const bf16x8* __restrict__ YG,
                                                      float* __restrict__ pnum) {
    __shared__ bf16x8 Bsh[2][1088];   // double-buffered 32x272 bf16 tiles (34816 B)
    int tid = threadIdx.x, wid = tid >> 6, lane = tid & 63;
    int l15 = lane & 15, l4 = lane >> 4;

    // bijective kc-major XCD swizzle (m204): 942 = 8*117 + 6 -> <=2 YG slices per XCD L2
    int orig = blockIdx.x;
    const int nwg = MB64 * KSPLIT, q = nwg >> 3, r = nwg & 7;
    int x = orig & 7, o = orig >> 3;
    int logical = (x < r ? x * (q + 1) : r * (q + 1) + (x - r) * q) + o;
    int kc = logical / MB64, mb = logical % MB64;
    int s0 = (kc * KSTEPS) / KSPLIT, s1 = ((kc + 1) * KSTEPS) / KSPLIT;

    // A addressing: wave owns rows mb*64+wid*16 .. +15; lane row = l15, k-group = l4*8
    const int* pR = adj + (size_t)min(mb * 64 + wid * 16 + l15, NN - 1) * 10000;
    int kgrp = l4 * 8;

    f32x4 acc[17];
#pragma unroll
    for (int ct = 0; ct < 17; ++ct) acc[ct] = f32x4{0.f, 0.f, 0.f, 0.f};

    int4 aA[2];   // one A-frag (16 rows x 32 k), reloaded in place 1 step ahead

    auto stageB = [&](int sTile, int bufIdx) {
        const bf16x8* src = YG + (size_t)sTile * 1088;
        char* dst = (char*)&Bsh[bufIdx][0];
#pragma unroll
        for (int i = 0; i < 5; ++i) {
            int rr = wid + i * 4;
            if (rr < 17) gl_lds16(src + rr * 64 + lane, dst + rr * 1024);  // wave0: 5, others: 4
        }
    };
    auto loadA = [&](int sTile) {
        int kk = min(sTile * 32 + kgrp, 9992);   // clamp safe: B is 0 for k>=NN
        const int4* p = (const int4*)(pR + kk);
        aA[0] = p[0]; aA[1] = p[1];
    };
    auto compute = [&](bf16x8 fa, int bufIdx) {
#pragma unroll
        for (int ct = 0; ct < 17; ++ct) {
            bf16x8 fb = Bsh[bufIdx][l4 * 272 + ct * 16 + l15];
            acc[ct] = __builtin_amdgcn_mfma_f32_16x16x32_bf16(fa, fb, acc[ct], 0, 0, 0);
        }
    };

    // ---- prologue: stage B(s0), issue A(s0) ----
    stageB(s0, 0);
    __builtin_amdgcn_sched_barrier(0);
    loadA(s0);
    asm volatile("s_waitcnt vmcnt(2)" ::: "memory");   // drain own B(s0) gl_lds; keep A(s0)
    __builtin_amdgcn_s_barrier();

    // ---- main loop: stage B(s+1); cvt A(s); reload A(s+1) in place; MFMA; counted wait ----
    int buf = 0;
    for (int s = s0; s < s1 - 1; ++s) {
        stageB(s + 1, buf ^ 1);
        __builtin_amdgcn_sched_barrier(0);
        bf16x8 fa = cvt_adj(aA[0], aA[1]);
        loadA(s + 1);                                   // WAR: ordered after cvt reads
        compute(fa, buf);
        asm volatile("s_waitcnt vmcnt(2)" ::: "memory");  // drain own B(s+1); keep A(s+1)
        __builtin_amdgcn_s_barrier();
        buf ^= 1;
    }
    // tail step s1-1: B staged + barrier'd; A in flight (compiler inserts its wait)
    {
        bf16x8 fa = cvt_adj(aA[0], aA[1]);
        compute(fa, buf);
    }

    // ---- epilogue: plain stores to per-kc partial buffer ----
    float* base = pnum + (size_t)kc * 10000 * 272;
    int r0 = mb * 64 + wid * 16;
#pragma unroll
    for (int ct = 0; ct < 17; ++ct) {
        int col = ct * 16 + l15;
#pragma unroll
        for (int rg = 0; rg < 4; ++rg) {
            int row = r0 + l4 * 4 + rg;
            if (row < NN) base[(size_t)row * 272 + col] = acc[ct][rg];
        }
    }
}

// ---------------- K5: out = (sum_kc num_kc) / max(sum_kc den_kc, 1e-30) ----------------
__global__ __launch_bounds__(256) void k_finalize(const float* __restrict__ pnum,
                                                  float* __restrict__ out) {
    int idx = blockIdx.x * 256 + threadIdx.x;   // 0..639999 (float4 units)
    int i = idx >> 6, q = idx & 63;
    float4 sv = {0.f, 0.f, 0.f, 0.f};
    float den = 0.f;
#pragma unroll
    for (int kc = 0; kc < KSPLIT; ++kc) {
        const float* row = pnum + ((size_t)kc * 10000 + i) * 272;
        float4 v = ((const float4*)row)[q];
        sv.x += v.x; sv.y += v.y; sv.z += v.z; sv.w += v.w;
        den += row[256];
    }
    float r = 1.0f / fmaxf(den, 1e-30f);
    float4 o;
    o.x = sv.x * r; o.y = sv.y * r; o.z = sv.z * r; o.w = sv.w * r;
    ((float4*)(out + (size_t)i * 256))[q] = o;
}

extern "C" void kernel_launch(void* const* d_in, const int* in_sizes, int n_in,
                              void* d_out, int out_size, void* d_ws, size_t ws_size,
                              hipStream_t stream) {
    const float* X    = (const float*)d_in[0];
    const int*   adj  = (const int*)d_in[1];
    const float* W    = (const float*)d_in[3];
    const float* bvec = (const float*)d_in[4];
    const float* avec = (const float*)d_in[5];
    float* out = (float*)d_out;

    char* ws = (char*)d_ws;
    bf16x8* XG   = (bf16x8*)(ws + XG_OFF);
    bf16x8* WG   = (bf16x8*)(ws + WG_OFF);
    float*  inp  = (float*)(ws + INP_OFF);
    float*  evec = (float*)(ws + E_OFF);
    float*  hsv  = (float*)(ws + HS_OFF);
    float*  gv   = (float*)(ws + G_OFF);
    bf16x8* YG   = (bf16x8*)(ws + YG_OFF);
    float*  pnum = (float*)(ws + PN_OFF);

    k_build_xg<<<1250, 256, 0, stream>>>(X, XG);
    k_build_wg<<<32, 256, 0, stream>>>(W, WG);
    k_gemm1<<<125, 256, 0, stream>>>(XG, WG, bvec, avec, inp, evec, hsv);
    k_softmax_g<<<1, 1024, 0, stream>>>(evec, hsv, gv);
    k_build_yg<<<318, 256, 0, stream>>>(inp, gv, YG);
    k_attn_gemm<<<MB64 * KSPLIT, 256, 0, stream>>>(adj, YG, pnum);
    k_finalize<<<2500, 256, 0, stream>>>(pnum, out);
}

// Round 10
// 203.615 us; speedup vs baseline: 1.1016x; 1.1016x over previous
//
#include <hip/hip_runtime.h>
#include <hip/hip_bf16.h>
#include <cstdint>
#include <cstddef>

// Problem constants (shapes fixed by the reference)
#define NN      10000      // nodes (M == N == 10000)
#define DD      256        // feature dim
#define KSTEPS  313        // ceil(10016/32) K-steps of 32
#define MB2     79         // ceil(10000/128) m-blocks for big GEMM (BM=128)
#define KSPLIT  6          // 79*6 = 474 blocks, 2/CU

typedef __bf16 bf16x8 __attribute__((ext_vector_type(8)));
typedef float  f32x4  __attribute__((ext_vector_type(4)));

// ---- workspace layout (bytes) ----
#define XG_OFF   0ull
#define XG_SIZE  (32ull * 10000 * 16)        // [q=kb*4+g][row] 16B chunks (bf16 X, MFMA-A layout)
#define WG_OFF   (XG_OFF + XG_SIZE)
#define WG_SIZE  (32ull * 256 * 16)          // [q][n] chunks (bf16 W, MFMA-B layout)
#define INP_OFF  (WG_OFF + WG_SIZE)
#define INP_SIZE (10000ull * 256 * 4)        // inp = X@W, f32
#define E_OFF    (INP_OFF + INP_SIZE)
#define E_SIZE   (10016ull * 4)
#define HS_OFF   (E_OFF + E_SIZE)
#define HS_SIZE  (10016ull * 4)
#define G_OFF    (HS_OFF + HS_SIZE)
#define G_SIZE   (10016ull * 4)
#define YG_OFF   (G_OFF + G_SIZE + 256ull)   // keep 256B alignment
#define YG_SIZE  (318ull * 1088 * 16)        // [kb32][chunk]; kb 313..317 zero pads (3-deep prefetch safe)
#define PN_OFF   (YG_OFF + YG_SIZE)
#define PN_SIZE  ((size_t)KSPLIT * 10000 * 272 * 4)  // per-kc partials: 256 numer cols + den at col 256

// async global(16B) -> LDS copy; dest = wave-uniform base + lane*16
__device__ __forceinline__ void gl_lds16(const void* g, void* lds) {
    __builtin_amdgcn_global_load_lds(
        (const __attribute__((address_space(1))) unsigned int*)g,
        (__attribute__((address_space(3))) unsigned int*)lds,
        16, 0, 0);
}

// ---------------- K0a: build XG (bf16 X in MFMA-A chunk layout) ----------------
__global__ __launch_bounds__(256) void k_build_xg(const float* __restrict__ X,
                                                  bf16x8* __restrict__ XG) {
    int idx = blockIdx.x * 256 + threadIdx.x;   // 0..319999
    int row = idx >> 5;
    int q   = idx & 31;
    const float* src = X + row * 256 + q * 8;
    bf16x8 v;
#pragma unroll
    for (int j = 0; j < 8; ++j) v[j] = (__bf16)src[j];
    XG[q * 10000 + row] = v;
}

// ---------------- K0b: build WG (bf16 W in MFMA-B chunk layout) ----------------
__global__ __launch_bounds__(256) void k_build_wg(const float* __restrict__ W,
                                                  bf16x8* __restrict__ WG) {
    int e = blockIdx.x * 256 + threadIdx.x;     // 0..8191
    int q = e >> 8;
    int n = e & 255;
    bf16x8 v;
#pragma unroll
    for (int j = 0; j < 8; ++j) v[j] = (__bf16)W[(q * 8 + j) * 256 + n];
    WG[e] = v;
}

// ---------------- K1: inp = X@W (MFMA), fused tanh/e/hsum (LDS cross-wave reduce) ----------------
__global__ __launch_bounds__(256) void k_gemm1(const bf16x8* __restrict__ XG,
                                               const bf16x8* __restrict__ WG,
                                               const float* __restrict__ bvec,
                                               const float* __restrict__ avec,
                                               float* __restrict__ inp,
                                               float* __restrict__ evec,
                                               float* __restrict__ hsumv) {
    __shared__ bf16x8 Ash[320];    // (g*80 + r)
    __shared__ bf16x8 Bsh[1024];   // (g*256 + n)
    __shared__ float ePart[4][80];
    __shared__ float hPart[4][80];
    int tid = threadIdx.x, wid = tid >> 6, lane = tid & 63;
    int l15 = lane & 15, l4 = lane >> 4;
    int mb = blockIdx.x;

    f32x4 acc[4][5];
#pragma unroll
    for (int c = 0; c < 4; ++c)
#pragma unroll
        for (int rt = 0; rt < 5; ++rt) acc[c][rt] = f32x4{0.f, 0.f, 0.f, 0.f};

    for (int kb = 0; kb < 8; ++kb) {
        for (int rr = wid; rr < 5; rr += 4) {
            int c = rr * 64 + lane;
            int g = c / 80, r = c - g * 80;
            gl_lds16(XG + ((kb * 4 + g) * 10000 + mb * 80 + r), (char*)Ash + rr * 1024);
        }
        for (int rr = wid; rr < 16; rr += 4)
            gl_lds16(WG + kb * 1024 + rr * 64 + lane, (char*)Bsh + rr * 1024);
        __syncthreads();

        bf16x8 af[5];
#pragma unroll
        for (int rt = 0; rt < 5; ++rt) af[rt] = Ash[l4 * 80 + rt * 16 + l15];
#pragma unroll
        for (int c = 0; c < 4; ++c) {
            bf16x8 bf = Bsh[l4 * 256 + (wid * 4 + c) * 16 + l15];
#pragma unroll
            for (int rt = 0; rt < 5; ++rt)
                acc[c][rt] = __builtin_amdgcn_mfma_f32_16x16x32_bf16(af[rt], bf, acc[c][rt], 0, 0, 0);
        }
        __syncthreads();
    }

    float pe[5][4], ph[5][4];
#pragma unroll
    for (int rt = 0; rt < 5; ++rt)
#pragma unroll
        for (int rg = 0; rg < 4; ++rg) { pe[rt][rg] = 0.f; ph[rt][rg] = 0.f; }

#pragma unroll
    for (int c = 0; c < 4; ++c) {
        int col = (wid * 4 + c) * 16 + l15;
        float av = avec[col];
        float bv = bvec[col];
#pragma unroll
        for (int rt = 0; rt < 5; ++rt) {
#pragma unroll
            for (int rg = 0; rg < 4; ++rg) {
                int row = mb * 80 + rt * 16 + l4 * 4 + rg;
                float v = acc[c][rt][rg];            // inp excludes bias (per reference)
                inp[row * 256 + col] = v;
                float h = tanhf(v + bv);
                pe[rt][rg] += h * av;
                ph[rt][rg] += h;
            }
        }
    }
#pragma unroll
    for (int rt = 0; rt < 5; ++rt) {
#pragma unroll
        for (int rg = 0; rg < 4; ++rg) {
            float se = pe[rt][rg], sh = ph[rt][rg];
#pragma unroll
            for (int m = 1; m < 16; m <<= 1) {
                se += __shfl_xor(se, m);
                sh += __shfl_xor(sh, m);
            }
            if (l15 == 0) {
                int lr = rt * 16 + l4 * 4 + rg;   // 0..79
                ePart[wid][lr] = se;
                hPart[wid][lr] = sh;
            }
        }
    }
    __syncthreads();
    if (tid < 80) {
        float e = ePart[0][tid] + ePart[1][tid] + ePart[2][tid] + ePart[3][tid];
        float h = hPart[0][tid] + hPart[1][tid] + hPart[2][tid] + hPart[3][tid];
        evec[mb * 80 + tid] = e;
        hsumv[mb * 80 + tid] = h;
    }
}

// ---------------- K2: global max of e over valid nodes, then g = exp(e-gmax) ----------------
__global__ __launch_bounds__(1024) void k_softmax_g(const float* __restrict__ evec,
                                                    const float* __restrict__ hsumv,
                                                    float* __restrict__ gv) {
    __shared__ float red[1024];
    int tid = threadIdx.x;
    float m = -3.0e38f;
    for (int i = tid; i < NN; i += 1024)
        if (hsumv[i] != 0.0f) m = fmaxf(m, evec[i]);
    red[tid] = m;
    __syncthreads();
    for (int s = 512; s > 0; s >>= 1) {
        if (tid < s) red[tid] = fmaxf(red[tid], red[tid + s]);
        __syncthreads();
    }
    float gmax = red[0];
    if (gmax < -1.0e37f) gmax = 0.0f;
    for (int i = tid; i < 10016; i += 1024) {
        float g = 0.0f;
        if (i < NN && hsumv[i] != 0.0f) g = expf(evec[i] - gmax);
        gv[i] = g;
    }
}

// ---------------- K3: build YG = pre-chunked bf16 B tiles for the big GEMM ----------------
// grid 318: kb >= 313 hits the k<NN guard everywhere -> zero pads
__global__ __launch_bounds__(256) void k_build_yg(const float* __restrict__ inp,
                                                  const float* __restrict__ gv,
                                                  bf16x8* __restrict__ YG) {
    int kb = blockIdx.x;   // 0..317
    for (int c = threadIdx.x; c < 1088; c += 256) {
        int gq = c / 272, n = c - gq * 272;
        int k0 = kb * 32 + gq * 8;
        bf16x8 v;
#pragma unroll
        for (int j = 0; j < 8; ++j) {
            int k = k0 + j;
            float val = 0.0f;
            if (k < NN) {
                float gk = gv[k];
                if (n < 256) val = gk * inp[k * 256 + n];
                else if (n == 256) val = gk;
            }
            v[j] = (__bf16)val;
        }
        YG[kb * 1088 + c] = v;
    }
}

// ---- int32 {0,1} pair-of-int4 -> bf16x8 {0,1} fragment ----
__device__ __forceinline__ bf16x8 cvt_adj(int4 a, int4 b) {
    union { bf16x8 v; unsigned int u[4]; } r;
    r.u[0] = (a.x > 0 ? 0x3F80u : 0u) | (a.y > 0 ? 0x3F800000u : 0u);
    r.u[1] = (a.z > 0 ? 0x3F80u : 0u) | (a.w > 0 ? 0x3F800000u : 0u);
    r.u[2] = (b.x > 0 ? 0x3F80u : 0u) | (b.y > 0 ? 0x3F800000u : 0u);
    r.u[3] = (b.z > 0 ? 0x3F80u : 0u) | (b.w > 0 ? 0x3F800000u : 0u);
    return r.v;
}

// ---------------- K4: num_kc = adj @ Y  (DEEP B-PIPELINE: 4 buffers, 3 steps of flight) ----------------
// BM=128: 4 waves x 32 rows (2 row-tiles), all 17 col-tiles, BK=32 -> 34 MFMA/wave/step.
// B: 4 LDS buffers (69.6 KB), stage B(s+3) each step -> every stage has ~3 steps of
// flight before its consumer. A: depth-2 ping-pong regs (R8). In-order vmcnt means
// cvt(A(s))'s compiler-inserted wait (A(s) was issued AFTER stage(s+1), two bodies
// ago) retires stage(s+1) automatically -> NO explicit vmcnt in the loop; one
// barrier/step. kc-major bijective XCD swizzle -> YG slice (<=1.84 MB) L2-resident.
__global__ __launch_bounds__(256, 2) void k_attn_gemm(const int* __restrict__ adj,
                                                      const bf16x8* __restrict__ YG,
                                                      float* __restrict__ pnum) {
    __shared__ bf16x8 Bsh[4][1088];   // 4 x 17408 B = 69632 B
    int tid = threadIdx.x, wid = tid >> 6, lane = tid & 63;
    int l15 = lane & 15, l4 = lane >> 4;

    // bijective kc-major XCD swizzle (m204): 474 = 8*59 + 2
    int orig = blockIdx.x;
    const int nwg = MB2 * KSPLIT, q = nwg >> 3, r = nwg & 7;
    int x = orig & 7, o = orig >> 3;
    int logical = (x < r ? x * (q + 1) : r * (q + 1) + (x - r) * q) + o;
    int kc = logical / MB2, mb = logical % MB2;   // kc-major: <=2 kc slices per XCD
    int s0 = (kc * KSTEPS) / KSPLIT, s1 = ((kc + 1) * KSTEPS) / KSPLIT;

    // A addressing: row = l15 (+16 for tile1), k-group = l4*8 (verified A-frag layout)
    int mrow = mb * 128 + wid * 32 + l15;
    const int* pA = adj + (size_t)min(mrow, NN - 1) * 10000;
    const int* pB = adj + (size_t)min(mrow + 16, NN - 1) * 10000;
    int kgrp = l4 * 8;

    f32x4 acc[2][17];
#pragma unroll
    for (int t = 0; t < 2; ++t)
#pragma unroll
        for (int ct = 0; ct < 17; ++ct) acc[t][ct] = f32x4{0.f, 0.f, 0.f, 0.f};

    int4 aA[4], aB[4];   // 2 ping-pong sets: 2 row-tiles x 2 int4 (32 k) each

    auto stageB = [&](int sTile, int bufIdx) {
        const bf16x8* src = YG + (size_t)sTile * 1088;
        char* dst = (char*)&Bsh[bufIdx][0];
#pragma unroll
        for (int i = 0; i < 5; ++i) {
            int rr = wid + i * 4;
            if (rr < 17) gl_lds16(src + rr * 64 + lane, dst + rr * 1024);  // wave0: 5, others: 4
        }
    };
    auto loadA = [&](int sTile, int4* dstA) {
        int kk = min(sTile * 32 + kgrp, 9992);   // clamp safe: B is 0 for k>=NN
        const int4* q0 = (const int4*)(pA + kk);
        const int4* q1 = (const int4*)(pB + kk);
        dstA[0] = q0[0]; dstA[1] = q0[1]; dstA[2] = q1[0]; dstA[3] = q1[1];
    };
    auto compute = [&](bf16x8 fa0, bf16x8 fa1, int bufIdx) {
#pragma unroll
        for (int ct = 0; ct < 17; ++ct) {
            bf16x8 fb = Bsh[bufIdx][l4 * 272 + ct * 16 + l15];
            acc[0][ct] = __builtin_amdgcn_mfma_f32_16x16x32_bf16(fa0, fb, acc[0][ct], 0, 0, 0);
            acc[1][ct] = __builtin_amdgcn_mfma_f32_16x16x32_bf16(fa1, fb, acc[1][ct], 0, 0, 0);
        }
    };

    // ---- prologue: stage B(s0..s0+2); issue A(s0),A(s0+1); drain stages, keep A ----
    stageB(s0,     (s0)     & 3);
    stageB(s0 + 1, (s0 + 1) & 3);
    stageB(s0 + 2, (s0 + 2) & 3);
    __builtin_amdgcn_sched_barrier(0);
    loadA(s0, aA);
    loadA(s0 + 1, aB);
    asm volatile("s_waitcnt vmcnt(8)" ::: "memory");   // drain all 3 stage sets; keep A(s0),A(s0+1)
    __builtin_amdgcn_s_barrier();

    // ---- main loop (2-unrolled ping-pong). Per body: stage(s+3); cvt A(s) [implicit
    // vmcnt retires stage(s+1) -> visible for next step]; reload set with A(s+2);
    // 34 MFMA; barrier. No explicit waitcnt: all waits are on >=2-step-old loads. ----
    int s = s0;
#define K4_BODY(ASET)                                                          \
    {                                                                          \
        stageB(s + 3, (s + 3) & 3);                                            \
        __builtin_amdgcn_sched_barrier(0);                                     \
        bf16x8 fa0 = cvt_adj(ASET[0], ASET[1]);                                \
        bf16x8 fa1 = cvt_adj(ASET[2], ASET[3]);                                \
        loadA(s + 2, ASET);                                                    \
        __builtin_amdgcn_sched_barrier(0);                                     \
        compute(fa0, fa1, s & 3);                                              \
        asm volatile("" ::: "memory");                                         \
        __builtin_amdgcn_s_barrier();                                          \
        ++s;                                                                   \
    }
    while (s + 2 <= s1) {
        K4_BODY(aA)
        K4_BODY(aB)
    }
#undef K4_BODY
    if (s < s1) {   // odd tail: B(s) staged+barrier'd; A(s) sits in aA
        bf16x8 fa0 = cvt_adj(aA[0], aA[1]);
        bf16x8 fa1 = cvt_adj(aA[2], aA[3]);
        compute(fa0, fa1, s & 3);
    }

    // ---- epilogue: plain stores to per-kc partial buffer ----
    float* base = pnum + (size_t)kc * 10000 * 272;
    int r0 = mb * 128 + wid * 32;
#pragma unroll
    for (int t = 0; t < 2; ++t) {
#pragma unroll
        for (int ct = 0; ct < 17; ++ct) {
            int col = ct * 16 + l15;
#pragma unroll
            for (int rg = 0; rg < 4; ++rg) {
                int row = r0 + t * 16 + l4 * 4 + rg;
                if (row < NN) base[(size_t)row * 272 + col] = acc[t][ct][rg];
            }
        }
    }
}

// ---------------- K5: out = (sum_kc num_kc) / max(sum_kc den_kc, 1e-30) ----------------
__global__ __launch_bounds__(256) void k_finalize(const float* __restrict__ pnum,
                                                  float* __restrict__ out) {
    int idx = blockIdx.x * 256 + threadIdx.x;   // 0..639999 (float4 units)
    int i = idx >> 6, q = idx & 63;
    float4 sv = {0.f, 0.f, 0.f, 0.f};
    float den = 0.f;
#pragma unroll
    for (int kc = 0; kc < KSPLIT; ++kc) {
        const float* row = pnum + ((size_t)kc * 10000 + i) * 272;
        float4 v = ((const float4*)row)[q];
        sv.x += v.x; sv.y += v.y; sv.z += v.z; sv.w += v.w;
        den += row[256];
    }
    float r = 1.0f / fmaxf(den, 1e-30f);
    float4 o;
    o.x = sv.x * r; o.y = sv.y * r; o.z = sv.z * r; o.w = sv.w * r;
    ((float4*)(out + (size_t)i * 256))[q] = o;
}

extern "C" void kernel_launch(void* const* d_in, const int* in_sizes, int n_in,
                              void* d_out, int out_size, void* d_ws, size_t ws_size,
                              hipStream_t stream) {
    const float* X    = (const float*)d_in[0];
    const int*   adj  = (const int*)d_in[1];
    const float* W    = (const float*)d_in[3];
    const float* bvec = (const float*)d_in[4];
    const float* avec = (const float*)d_in[5];
    float* out = (float*)d_out;

    char* ws = (char*)d_ws;
    bf16x8* XG   = (bf16x8*)(ws + XG_OFF);
    bf16x8* WG   = (bf16x8*)(ws + WG_OFF);
    float*  inp  = (float*)(ws + INP_OFF);
    float*  evec = (float*)(ws + E_OFF);
    float*  hsv  = (float*)(ws + HS_OFF);
    float*  gv   = (float*)(ws + G_OFF);
    bf16x8* YG   = (bf16x8*)(ws + YG_OFF);
    float*  pnum = (float*)(ws + PN_OFF);

    k_build_xg<<<1250, 256, 0, stream>>>(X, XG);
    k_build_wg<<<32, 256, 0, stream>>>(W, WG);
    k_gemm1<<<125, 256, 0, stream>>>(XG, WG, bvec, avec, inp, evec, hsv);
    k_softmax_g<<<1, 1024, 0, stream>>>(evec, hsv, gv);
    k_build_yg<<<318, 256, 0, stream>>>(inp, gv, YG);
    k_attn_gemm<<<MB2 * KSPLIT, 256, 0, stream>>>(adj, YG, pnum);
    k_finalize<<<2500, 256, 0, stream>>>(pnum, out);
}

// Round 11
// 191.804 us; speedup vs baseline: 1.1695x; 1.0616x over previous
//
#include <hip/hip_runtime.h>
#include <hip/hip_bf16.h>
#include <cstdint>
#include <cstddef>

// Problem constants (shapes fixed by the reference)
#define NN      10000      // nodes (M == N == 10000)
#define DD      256        // feature dim
#define KSTEPS  313        // ceil(10016/32) K-steps of 32
#define MB2     79         // ceil(10000/128) m-blocks for big GEMM (BM=128)
#define KSPLIT  6          // 79*6 = 474 blocks, 2/CU

typedef __bf16 bf16x8 __attribute__((ext_vector_type(8)));
typedef float  f32x4  __attribute__((ext_vector_type(4)));

// ---- workspace layout (bytes) ----
#define XG_OFF   0ull
#define XG_SIZE  (32ull * 10000 * 16)        // [q=kb*4+g][row] 16B chunks (bf16 X, MFMA-A layout)
#define WG_OFF   (XG_OFF + XG_SIZE)
#define WG_SIZE  (32ull * 256 * 16)          // [q][n] chunks (bf16 W, MFMA-B layout)
#define INP_OFF  (WG_OFF + WG_SIZE)
#define INP_SIZE (10000ull * 256 * 4)        // inp = X@W, f32
#define E_OFF    (INP_OFF + INP_SIZE)
#define E_SIZE   (10016ull * 4)
#define HS_OFF   (E_OFF + E_SIZE)
#define HS_SIZE  (10016ull * 4)
#define G_OFF    (HS_OFF + HS_SIZE)
#define G_SIZE   (10016ull * 4)
#define YG_OFF   (G_OFF + G_SIZE + 256ull)   // keep 256B alignment
#define YG_SIZE  (318ull * 1088 * 16)        // [kb32][chunk]; kb 313..317 zero pads
#define PN_OFF   (YG_OFF + YG_SIZE)
#define PN_SIZE  ((size_t)KSPLIT * 10000 * 272 * 4)  // per-kc partials: 256 numer cols + den at col 256

// async global(16B) -> LDS copy; dest = wave-uniform base + lane*16
__device__ __forceinline__ void gl_lds16(const void* g, void* lds) {
    __builtin_amdgcn_global_load_lds(
        (const __attribute__((address_space(1))) unsigned int*)g,
        (__attribute__((address_space(3))) unsigned int*)lds,
        16, 0, 0);
}

// ---------------- K0a: build XG (bf16 X in MFMA-A chunk layout) ----------------
__global__ __launch_bounds__(256) void k_build_xg(const float* __restrict__ X,
                                                  bf16x8* __restrict__ XG) {
    int idx = blockIdx.x * 256 + threadIdx.x;   // 0..319999
    int row = idx >> 5;
    int q   = idx & 31;
    const float* src = X + row * 256 + q * 8;
    bf16x8 v;
#pragma unroll
    for (int j = 0; j < 8; ++j) v[j] = (__bf16)src[j];
    XG[q * 10000 + row] = v;
}

// ---------------- K0b: build WG (bf16 W in MFMA-B chunk layout) ----------------
__global__ __launch_bounds__(256) void k_build_wg(const float* __restrict__ W,
                                                  bf16x8* __restrict__ WG) {
    int e = blockIdx.x * 256 + threadIdx.x;     // 0..8191
    int q = e >> 8;
    int n = e & 255;
    bf16x8 v;
#pragma unroll
    for (int j = 0; j < 8; ++j) v[j] = (__bf16)W[(q * 8 + j) * 256 + n];
    WG[e] = v;
}

// ---------------- K1: inp = X@W (MFMA), fused tanh/e/hsum (LDS cross-wave reduce) ----------------
__global__ __launch_bounds__(256) void k_gemm1(const bf16x8* __restrict__ XG,
                                               const bf16x8* __restrict__ WG,
                                               const float* __restrict__ bvec,
                                               const float* __restrict__ avec,
                                               float* __restrict__ inp,
                                               float* __restrict__ evec,
                                               float* __restrict__ hsumv) {
    __shared__ bf16x8 Ash[320];    // (g*80 + r)
    __shared__ bf16x8 Bsh[1024];   // (g*256 + n)
    __shared__ float ePart[4][80];
    __shared__ float hPart[4][80];
    int tid = threadIdx.x, wid = tid >> 6, lane = tid & 63;
    int l15 = lane & 15, l4 = lane >> 4;
    int mb = blockIdx.x;

    f32x4 acc[4][5];
#pragma unroll
    for (int c = 0; c < 4; ++c)
#pragma unroll
        for (int rt = 0; rt < 5; ++rt) acc[c][rt] = f32x4{0.f, 0.f, 0.f, 0.f};

    for (int kb = 0; kb < 8; ++kb) {
        for (int rr = wid; rr < 5; rr += 4) {
            int c = rr * 64 + lane;
            int g = c / 80, r = c - g * 80;
            gl_lds16(XG + ((kb * 4 + g) * 10000 + mb * 80 + r), (char*)Ash + rr * 1024);
        }
        for (int rr = wid; rr < 16; rr += 4)
            gl_lds16(WG + kb * 1024 + rr * 64 + lane, (char*)Bsh + rr * 1024);
        __syncthreads();

        bf16x8 af[5];
#pragma unroll
        for (int rt = 0; rt < 5; ++rt) af[rt] = Ash[l4 * 80 + rt * 16 + l15];
#pragma unroll
        for (int c = 0; c < 4; ++c) {
            bf16x8 bf = Bsh[l4 * 256 + (wid * 4 + c) * 16 + l15];
#pragma unroll
            for (int rt = 0; rt < 5; ++rt)
                acc[c][rt] = __builtin_amdgcn_mfma_f32_16x16x32_bf16(af[rt], bf, acc[c][rt], 0, 0, 0);
        }
        __syncthreads();
    }

    float pe[5][4], ph[5][4];
#pragma unroll
    for (int rt = 0; rt < 5; ++rt)
#pragma unroll
        for (int rg = 0; rg < 4; ++rg) { pe[rt][rg] = 0.f; ph[rt][rg] = 0.f; }

#pragma unroll
    for (int c = 0; c < 4; ++c) {
        int col = (wid * 4 + c) * 16 + l15;
        float av = avec[col];
        float bv = bvec[col];
#pragma unroll
        for (int rt = 0; rt < 5; ++rt) {
#pragma unroll
            for (int rg = 0; rg < 4; ++rg) {
                int row = mb * 80 + rt * 16 + l4 * 4 + rg;
                float v = acc[c][rt][rg];            // inp excludes bias (per reference)
                inp[row * 256 + col] = v;
                float h = tanhf(v + bv);
                pe[rt][rg] += h * av;
                ph[rt][rg] += h;
            }
        }
    }
#pragma unroll
    for (int rt = 0; rt < 5; ++rt) {
#pragma unroll
        for (int rg = 0; rg < 4; ++rg) {
            float se = pe[rt][rg], sh = ph[rt][rg];
#pragma unroll
            for (int m = 1; m < 16; m <<= 1) {
                se += __shfl_xor(se, m);
                sh += __shfl_xor(sh, m);
            }
            if (l15 == 0) {
                int lr = rt * 16 + l4 * 4 + rg;   // 0..79
                ePart[wid][lr] = se;
                hPart[wid][lr] = sh;
            }
        }
    }
    __syncthreads();
    if (tid < 80) {
        float e = ePart[0][tid] + ePart[1][tid] + ePart[2][tid] + ePart[3][tid];
        float h = hPart[0][tid] + hPart[1][tid] + hPart[2][tid] + hPart[3][tid];
        evec[mb * 80 + tid] = e;
        hsumv[mb * 80 + tid] = h;
    }
}

// ---------------- K2: global max of e over valid nodes, then g = exp(e-gmax) ----------------
__global__ __launch_bounds__(1024) void k_softmax_g(const float* __restrict__ evec,
                                                    const float* __restrict__ hsumv,
                                                    float* __restrict__ gv) {
    __shared__ float red[1024];
    int tid = threadIdx.x;
    float m = -3.0e38f;
    for (int i = tid; i < NN; i += 1024)
        if (hsumv[i] != 0.0f) m = fmaxf(m, evec[i]);
    red[tid] = m;
    __syncthreads();
    for (int s = 512; s > 0; s >>= 1) {
        if (tid < s) red[tid] = fmaxf(red[tid], red[tid + s]);
        __syncthreads();
    }
    float gmax = red[0];
    if (gmax < -1.0e37f) gmax = 0.0f;
    for (int i = tid; i < 10016; i += 1024) {
        float g = 0.0f;
        if (i < NN && hsumv[i] != 0.0f) g = expf(evec[i] - gmax);
        gv[i] = g;
    }
}

// ---------------- K3: build YG = pre-chunked bf16 B tiles for the big GEMM ----------------
// grid 318: kb >= 313 hits the k<NN guard everywhere -> zero pads
__global__ __launch_bounds__(256) void k_build_yg(const float* __restrict__ inp,
                                                  const float* __restrict__ gv,
                                                  bf16x8* __restrict__ YG) {
    int kb = blockIdx.x;   // 0..317
    for (int c = threadIdx.x; c < 1088; c += 256) {
        int gq = c / 272, n = c - gq * 272;
        int k0 = kb * 32 + gq * 8;
        bf16x8 v;
#pragma unroll
        for (int j = 0; j < 8; ++j) {
            int k = k0 + j;
            float val = 0.0f;
            if (k < NN) {
                float gk = gv[k];
                if (n < 256) val = gk * inp[k * 256 + n];
                else if (n == 256) val = gk;
            }
            v[j] = (__bf16)val;
        }
        YG[kb * 1088 + c] = v;
    }
}

// ---- int32 {0,1} pair-of-int4 -> bf16x8 {0,1} fragment ----
__device__ __forceinline__ bf16x8 cvt_adj(int4 a, int4 b) {
    union { bf16x8 v; unsigned int u[4]; } r;
    r.u[0] = (a.x > 0 ? 0x3F80u : 0u) | (a.y > 0 ? 0x3F800000u : 0u);
    r.u[1] = (a.z > 0 ? 0x3F80u : 0u) | (a.w > 0 ? 0x3F800000u : 0u);
    r.u[2] = (b.x > 0 ? 0x3F80u : 0u) | (b.y > 0 ? 0x3F800000u : 0u);
    r.u[3] = (b.z > 0 ? 0x3F80u : 0u) | (b.w > 0 ? 0x3F800000u : 0u);
    return r.v;
}

// ---------------- K4: num_kc = adj @ Y  (ALL-ASYNC STAGING: A and B via gl_lds, m97 pattern) ----------------
// BM=128, BK=32, 4 waves x 32 rows (2 row-tiles), 17 col-tiles. BOTH operands staged
// into double-buffered LDS with global_load_lds (fire-and-forget): in-flight bytes per
// CU ~66 KB (2 blocks x 33 KB) vs ~2-5 KB with register-A — the R1-R10 plateau was
// outstanding-bytes starvation on the A-stream. One plain __syncthreads per step
// (compiler's vmcnt(0) drains stages issued a full compute-phase earlier); NO manual
// waitcnt. A-tile in LDS is XOR-swizzled (LDS[row][p] = Global[row][p ^ (row&7)]) via
// pre-swizzled per-lane global source (m201 both-sides pattern): staging stays fully
// line-coalesced (permutation within each 128B row-span), reads are conflict-free.
__global__ __launch_bounds__(256, 2) void k_attn_gemm(const int* __restrict__ adj,
                                                      const bf16x8* __restrict__ YG,
                                                      float* __restrict__ pnum) {
    __shared__ int    Ash[2][4096];   // [buf][row*32 + k'] ints: 2 x 16 KB (swizzled 16B chunks)
    __shared__ bf16x8 Bsh[2][1088];   // [buf] 32x272 bf16 tiles: 2 x 17 KB
    int tid = threadIdx.x, wid = tid >> 6, lane = tid & 63;
    int l15 = lane & 15, l4 = lane >> 4;

    // bijective kc-major XCD swizzle (m204): 474 = 8*59 + 2; <=2 YG slices per XCD L2
    int orig = blockIdx.x;
    const int nwg = MB2 * KSPLIT, q = nwg >> 3, r = nwg & 7;
    int x = orig & 7, o = orig >> 3;
    int logical = (x < r ? x * (q + 1) : r * (q + 1) + (x - r) * q) + o;
    int kc = logical / MB2, mb = logical % MB2;
    int s0 = (kc * KSTEPS) / KSPLIT, s1 = ((kc + 1) * KSTEPS) / KSPLIT;

    // ---- A staging precompute: 16 gl_lds instrs block-wide (4 per wave) ----
    // instr i covers chunks c = (wid+i*4)*64 + lane; chunk c -> row = c>>3, p = c&7;
    // LDS[row][p] holds global 16B-chunk (p ^ (row&7)) of the step's 32-int span.
    // Clamp engages exactly when target k >= 10000 (garbage x B=0 -> safe).
    const int* aSrc[4];
    int aLim[4];
#pragma unroll
    for (int i = 0; i < 4; ++i) {
        int c = (wid + i * 4) * 64 + lane;
        int row = c >> 3;
        int p = c & 7;
        int ck4 = (p ^ (row & 7)) * 4;               // global int offset within step span
        int grow = min(mb * 128 + row, NN - 1);
        aSrc[i] = adj + (size_t)grow * 10000 + ck4;
        aLim[i] = 9996 - ck4;                        // min(s*32, aLim) keeps all reads in row
    }

    f32x4 acc[2][17];
#pragma unroll
    for (int t = 0; t < 2; ++t)
#pragma unroll
        for (int ct = 0; ct < 17; ++ct) acc[t][ct] = f32x4{0.f, 0.f, 0.f, 0.f};

    auto stageA = [&](int sTile, int bufIdx) {
        int kk = sTile * 32;
        char* dst = (char*)&Ash[bufIdx][0];
#pragma unroll
        for (int i = 0; i < 4; ++i)
            gl_lds16(aSrc[i] + min(kk, aLim[i]), dst + (wid + i * 4) * 1024);
    };
    auto stageB = [&](int sTile, int bufIdx) {
        const bf16x8* src = YG + (size_t)sTile * 1088;
        char* dst = (char*)&Bsh[bufIdx][0];
#pragma unroll
        for (int i = 0; i < 5; ++i) {
            int rr = wid + i * 4;
            if (rr < 17) gl_lds16(src + rr * 64 + lane, dst + rr * 1024);  // wave0: 5, others: 4
        }
    };

    // A-frag read offsets (swizzled): row = wid*32 + rt*16 + l15 (row&7 == l15&7)
    int xr = l15 & 7;
    int p0 = (2 * l4) ^ xr;                 // LDS chunk holding global chunk 2*l4
    int rowA0 = wid * 32 + l15;             // rt=0 row; rt=1 adds 16 (doesn't change &7)

    // ---- prologue ----
    stageA(s0, 0);
    stageB(s0, 0);
    __syncthreads();

    // ---- main loop: one barrier per step, everything async ----
    int buf = 0;
    for (int s = s0; s < s1; ++s) {
        if (s + 1 < s1) {
            stageA(s + 1, buf ^ 1);
            stageB(s + 1, buf ^ 1);
        }
        // A fragments from swizzled LDS (conflict-free), convert to bf16 {0,1}
        const int* ab = &Ash[buf][0];
        int4 v00 = *(const int4*)(ab + rowA0 * 32 + p0 * 4);
        int4 v01 = *(const int4*)(ab + rowA0 * 32 + (p0 ^ 1) * 4);
        int4 v10 = *(const int4*)(ab + (rowA0 + 16) * 32 + p0 * 4);
        int4 v11 = *(const int4*)(ab + (rowA0 + 16) * 32 + (p0 ^ 1) * 4);
        bf16x8 fa0 = cvt_adj(v00, v01);
        bf16x8 fa1 = cvt_adj(v10, v11);
#pragma unroll
        for (int ct = 0; ct < 17; ++ct) {
            bf16x8 fb = Bsh[buf][l4 * 272 + ct * 16 + l15];
            acc[0][ct] = __builtin_amdgcn_mfma_f32_16x16x32_bf16(fa0, fb, acc[0][ct], 0, 0, 0);
            acc[1][ct] = __builtin_amdgcn_mfma_f32_16x16x32_bf16(fa1, fb, acc[1][ct], 0, 0, 0);
        }
        __syncthreads();
        buf ^= 1;
    }

    // ---- epilogue: plain stores to per-kc partial buffer ----
    float* base = pnum + (size_t)kc * 10000 * 272;
    int r0 = mb * 128 + wid * 32;
#pragma unroll
    for (int t = 0; t < 2; ++t) {
#pragma unroll
        for (int ct = 0; ct < 17; ++ct) {
            int col = ct * 16 + l15;
#pragma unroll
            for (int rg = 0; rg < 4; ++rg) {
                int row = r0 + t * 16 + l4 * 4 + rg;
                if (row < NN) base[(size_t)row * 272 + col] = acc[t][ct][rg];
            }
        }
    }
}

// ---------------- K5: out = (sum_kc num_kc) / max(sum_kc den_kc, 1e-30) ----------------
__global__ __launch_bounds__(256) void k_finalize(const float* __restrict__ pnum,
                                                  float* __restrict__ out) {
    int idx = blockIdx.x * 256 + threadIdx.x;   // 0..639999 (float4 units)
    int i = idx >> 6, q = idx & 63;
    float4 sv = {0.f, 0.f, 0.f, 0.f};
    float den = 0.f;
#pragma unroll
    for (int kc = 0; kc < KSPLIT; ++kc) {
        const float* row = pnum + ((size_t)kc * 10000 + i) * 272;
        float4 v = ((const float4*)row)[q];
        sv.x += v.x; sv.y += v.y; sv.z += v.z; sv.w += v.w;
        den += row[256];
    }
    float r = 1.0f / fmaxf(den, 1e-30f);
    float4 o;
    o.x = sv.x * r; o.y = sv.y * r; o.z = sv.z * r; o.w = sv.w * r;
    ((float4*)(out + (size_t)i * 256))[q] = o;
}

extern "C" void kernel_launch(void* const* d_in, const int* in_sizes, int n_in,
                              void* d_out, int out_size, void* d_ws, size_t ws_size,
                              hipStream_t stream) {
    const float* X    = (const float*)d_in[0];
    const int*   adj  = (const int*)d_in[1];
    const float* W    = (const float*)d_in[3];
    const float* bvec = (const float*)d_in[4];
    const float* avec = (const float*)d_in[5];
    float* out = (float*)d_out;

    char* ws = (char*)d_ws;
    bf16x8* XG   = (bf16x8*)(ws + XG_OFF);
    bf16x8* WG   = (bf16x8*)(ws + WG_OFF);
    float*  inp  = (float*)(ws + INP_OFF);
    float*  evec = (float*)(ws + E_OFF);
    float*  hsv  = (float*)(ws + HS_OFF);
    float*  gv   = (float*)(ws + G_OFF);
    bf16x8* YG   = (bf16x8*)(ws + YG_OFF);
    float*  pnum = (float*)(ws + PN_OFF);

    k_build_xg<<<1250, 256, 0, stream>>>(X, XG);
    k_build_wg<<<32, 256, 0, stream>>>(W, WG);
    k_gemm1<<<125, 256, 0, stream>>>(XG, WG, bvec, avec, inp, evec, hsv);
    k_softmax_g<<<1, 1024, 0, stream>>>(evec, hsv, gv);
    k_build_yg<<<318, 256, 0, stream>>>(inp, gv, YG);
    k_attn_gemm<<<MB2 * KSPLIT, 256, 0, stream>>>(adj, YG, pnum);
    k_finalize<<<2500, 256, 0, stream>>>(pnum, out);
}